// Round 7
// baseline (528.192 us; speedup 1.0000x reference)
//
#include <hip/hip_runtime.h>
#include <hip/hip_bf16.h>
#include <math.h>

#define G_GRAPHS 256
#define EPG 2048
#define E_TOT 524288
#define HF 256
#define FIN 128

// ============================================================================
__global__ void init_cur(int* __restrict__ cur) {
    int i = blockIdx.x * blockDim.x + threadIdx.x;
    if (i < G_GRAPHS * 256) cur[i] = i & 255;
}

// ---------------------------------------------------------------------------
// C[N x 256] = A[N x K] @ W[K x 256], fp32, k-ascending single-accumulator
// chains (bit-exact vs all previous versions).
// v10: LANE=ROW remap -> W is WAVE-UNIFORM and leaves the LDS pipe.
// R6 analysis: v6-v9 (62-70us) were LDS-instruction-throughput bound:
// 3 ds_read_b128/kk/wave x 12cy, one LDS pipe per CU vs 4 VALU SIMDs ->
// LDS oversubscribed 2.25x (= measured 62us vs 27.3us FMA wall).
//   * wave = 64 rows (lane=row) x 32 cols; block = 4 waves = 64 rows x 128 cols.
//   * W read via readfirstlane-uniform pointer -> s_load (scalar pipe);
//     v_fma takes the SGPR operand directly. Zero LDS traffic for W.
//   * A in LDS, transposed At[kk][68]: per-lane read = ds_read_b32 at
//     kk*68+lane (64 consecutive addrs, conflict-free, ~5.8cy/kk vs 36).
//   * A double-buffered (17KB), 1 barrier/tile, loads issued before compute.
// ---------------------------------------------------------------------------
template <int K>
__global__ __launch_bounds__(256, 4)
void gemm_v10(const float* __restrict__ A, const float* __restrict__ W,
              float* __restrict__ C) {
    __shared__ float As[2][32 * 68];   // [buf][kk][row(64)+pad]
    const int tid = threadIdx.x;
    const int lane = tid & 63;         // row within tile
    const int r0 = blockIdx.x * 64;
    const int cb = blockIdx.y * 128 + (tid >> 6) * 32;  // wave's col base
    const int cbu = __builtin_amdgcn_readfirstlane(cb);
    const float* __restrict__ Wu = W + cbu;
    const int sr = tid >> 2;           // staging row 0..63
    const int sq = tid & 3;            // staging quad 0..3
    float acc[32] = {};
    float4 va0, va1;

    auto load_regs = [&](int k0) {
        va0 = *(const float4*)&A[(size_t)(r0 + sr) * K + k0 + 4 * sq];
        va1 = *(const float4*)&A[(size_t)(r0 + sr) * K + k0 + 16 + 4 * sq];
    };
    auto write_stage = [&](int b) {
        // At[kk][sr]: banks (16*sq + sr + 68i) mod 32 -> 2-way max (free)
        float* p0 = &As[b][(4 * sq) * 68 + sr];
        p0[0]   = va0.x; p0[68]  = va0.y; p0[136] = va0.z; p0[204] = va0.w;
        float* p1 = &As[b][(16 + 4 * sq) * 68 + sr];
        p1[0]   = va1.x; p1[68]  = va1.y; p1[136] = va1.z; p1[204] = va1.w;
    };
    auto compute = [&](int b, int k0) {
#pragma unroll
        for (int kq = 0; kq < 8; ++kq) {
            float av[4];
#pragma unroll
            for (int u = 0; u < 4; ++u)
                av[u] = As[b][(4 * kq + u) * 68 + lane];
#pragma unroll
            for (int u = 0; u < 4; ++u) {
                const float* wr = &Wu[(size_t)(k0 + 4 * kq + u) * 256];
                float4 w0 = *(const float4*)&wr[0];
                float4 w1 = *(const float4*)&wr[4];
                float4 w2 = *(const float4*)&wr[8];
                float4 w3 = *(const float4*)&wr[12];
                float4 w4 = *(const float4*)&wr[16];
                float4 w5 = *(const float4*)&wr[20];
                float4 w6 = *(const float4*)&wr[24];
                float4 w7 = *(const float4*)&wr[28];
                const float wv_[32] = {
                    w0.x, w0.y, w0.z, w0.w, w1.x, w1.y, w1.z, w1.w,
                    w2.x, w2.y, w2.z, w2.w, w3.x, w3.y, w3.z, w3.w,
                    w4.x, w4.y, w4.z, w4.w, w5.x, w5.y, w5.z, w5.w,
                    w6.x, w6.y, w6.z, w6.w, w7.x, w7.y, w7.z, w7.w};
#pragma unroll
                for (int j = 0; j < 32; ++j)
                    acc[j] += av[u] * wv_[j];
            }
        }
    };

    load_regs(0);
    write_stage(0);
    __syncthreads();
    int cur = 0;
    for (int k0 = 0; k0 < K - 32; k0 += 32) {
        load_regs(k0 + 32);     // in flight under compute
        compute(cur, k0);
        write_stage(cur ^ 1);   // other buffer: no hazard
        __syncthreads();        // publish
        cur ^= 1;
    }
    compute(cur, K - 32);

    // epilogue: lane writes its row, cols cb..cb+31 (row-strided stores)
    const size_t base = (size_t)(r0 + lane) * 256 + cb;
#pragma unroll
    for (int j = 0; j < 32; j += 4)
        *(float4*)&C[base + j] =
            make_float4(acc[j], acc[j + 1], acc[j + 2], acc[j + 3]);
}

// ---------------------------------------------------------------------------
// Parallel STABLE counting-sort CSR with packed (src, dinv_src) slots.
// ---------------------------------------------------------------------------
__global__ __launch_bounds__(256)
void csr_build(const int* __restrict__ ei, const int* __restrict__ cur, int npg,
               int* __restrict__ degS, float* __restrict__ dinvS,
               int* __restrict__ startsS, int2* __restrict__ slots2) {
    __shared__ int cul[EPG];
    __shared__ short dstv[EPG];
    __shared__ unsigned char rnk[EPG];
    __shared__ int h[32][256];
    __shared__ int cnt[256];
    __shared__ int st[256];
    const int g = blockIdx.x;
    const int t = threadIdx.x;
    const int lane = t & 63;
    const int wv = t >> 6;

    for (int i = t; i < 32 * 256; i += 256) ((int*)h)[i] = 0;
    for (int e = t; e < EPG; e += 256) {
        size_t idx = (size_t)g * EPG + e;
        int cu = cur[g * 256 + (ei[idx] - g * 256)];
        int cv = cur[g * 256 + (ei[E_TOT + idx] - g * 256)];
        bool valid = (cu >= 0 && cv >= 0);
        cul[e] = cu;
        dstv[e] = valid ? (short)cv : (short)256;
    }
    __syncthreads();
    for (int c = wv; c < 32; c += 4) {
        int e = c * 64 + lane;
        int d = (int)dstv[e];
        unsigned long long m = ~0ULL;
#pragma unroll
        for (int b = 0; b < 9; ++b) {
            unsigned long long bb = __ballot((d >> b) & 1);
            m &= ((d >> b) & 1) ? bb : ~bb;
        }
        int r = __popcll(m & ((1ULL << lane) - 1ULL));
        rnk[e] = (unsigned char)r;
        if (r == 0 && d < 256) h[c][d] = __popcll(m);
    }
    __syncthreads();
    if (t < npg) {
        int run = 0;
        for (int c = 0; c < 32; ++c) { int v = h[c][t]; h[c][t] = run; run += v; }
        cnt[t] = run;
        degS[g * npg + t] = run + 1;
        dinvS[g * npg + t] = 1.0f / sqrtf((float)(run + 1));
    }
    __syncthreads();
    if (t == 0) {
        int run = 0;
        for (int i = 0; i < npg; ++i) { st[i] = run; run += cnt[i]; }
    }
    __syncthreads();
    if (t < npg) startsS[g * npg + t] = g * EPG + st[t];
    for (int e = t; e < EPG; e += 256) {
        int d = (int)dstv[e];
        if (d < npg) {
            int slot = st[d] + h[e >> 6][d] + (int)rnk[e];
            int cu = cul[e];
            float dv = 1.0f / sqrtf((float)(cnt[cu] + 1));   // == dinvS[src]
            slots2[g * EPG + slot] = make_int2(g * npg + cu, __float_as_int(dv));
        }
    }
}

// ---------------------------------------------------------------------------
// conv + relu + pool score, v2: ONE WAVE PER NODE, float4 per lane.
// (R2-proven: bit-exact, dropped agg from 70.6us out of the top-5.)
// ---------------------------------------------------------------------------
__global__ __launch_bounds__(256)
void agg_score2(const int* __restrict__ degS, const float* __restrict__ dinvS,
                const int* __restrict__ startsS, const int2* __restrict__ slots2,
                const float* __restrict__ HL, float* __restrict__ H2,
                const float* __restrict__ bias, const float* __restrict__ pw,
                float* __restrict__ score, int nbOver8) {
    __shared__ float vrow[4][256];
    const int t = threadIdx.x;
    const int wv = t >> 6;
    const int lane = t & 63;
    const int blk = (blockIdx.x & 7) * nbOver8 + (blockIdx.x >> 3);
    const int node = blk * 4 + wv;
    const int cntE = degS[node] - 1;
    const float degF = (float)(cntE + 1);
    const float dn = dinvS[node];
    const int2* sl = slots2 + startsS[node];
    float ax = 0.f, ay = 0.f, az = 0.f, aw = 0.f;
    int j = 0;
    for (; j + 8 <= cntE; j += 8) {
        int2 s[8];
#pragma unroll
        for (int u = 0; u < 8; ++u) s[u] = sl[j + u];
        float4 hv[8];
#pragma unroll
        for (int u = 0; u < 8; ++u)
            hv[u] = *(const float4*)&HL[(size_t)s[u].x * 256 + 4 * lane];
#pragma unroll
        for (int u = 0; u < 8; ++u) {
            float dv = __int_as_float(s[u].y);
            ax += dv * hv[u].x; ay += dv * hv[u].y;
            az += dv * hv[u].z; aw += dv * hv[u].w;
        }
    }
    for (; j + 4 <= cntE; j += 4) {
        int2 s[4];
#pragma unroll
        for (int u = 0; u < 4; ++u) s[u] = sl[j + u];
        float4 hv[4];
#pragma unroll
        for (int u = 0; u < 4; ++u)
            hv[u] = *(const float4*)&HL[(size_t)s[u].x * 256 + 4 * lane];
#pragma unroll
        for (int u = 0; u < 4; ++u) {
            float dv = __int_as_float(s[u].y);
            ax += dv * hv[u].x; ay += dv * hv[u].y;
            az += dv * hv[u].z; aw += dv * hv[u].w;
        }
    }
    for (; j < cntE; ++j) {
        int2 sv = sl[j];
        float dv = __int_as_float(sv.y);
        float4 hv = *(const float4*)&HL[(size_t)sv.x * 256 + 4 * lane];
        ax += dv * hv.x; ay += dv * hv.y; az += dv * hv.z; aw += dv * hv.w;
    }
    const float4 hn = *(const float4*)&HL[(size_t)node * 256 + 4 * lane];
    const float4 bi = *(const float4*)&bias[4 * lane];
    float4 v;
    v.x = ax * dn + hn.x / degF + bi.x;  v.x = fmaxf(v.x, 0.f);
    v.y = ay * dn + hn.y / degF + bi.y;  v.y = fmaxf(v.y, 0.f);
    v.z = az * dn + hn.z / degF + bi.z;  v.z = fmaxf(v.z, 0.f);
    v.w = aw * dn + hn.w / degF + bi.w;  v.w = fmaxf(v.w, 0.f);
    *(float4*)&H2[(size_t)node * 256 + 4 * lane] = v;
    *(float4*)&vrow[wv][4 * lane] = v;
    // same-wave LDS RAW: compiler inserts the lgkmcnt; no cross-wave sharing.
    float pr = 0.f, s2p = 0.f;
    for (int jj = 0; jj < 4; ++jj) {
        int f = lane + 64 * jj;
        float w = pw[f];
        pr += vrow[wv][f] * w;
        s2p += w * w;
    }
    for (int off = 32; off; off >>= 1) {
        pr += __shfl_down(pr, off, 64);
        s2p += __shfl_down(s2p, off, 64);
    }
    s2p = __shfl(s2p, 0, 64);
    if (lane == 0) score[node] = tanhf(pr / sqrtf(s2p));
}

// ---------------------------------------------------------------------------
// topk + cur update + pool + readout, FUSED (R5-proven, bit-exact).
// ---------------------------------------------------------------------------
__global__ __launch_bounds__(256)
void topk_fused(const float* __restrict__ score, int npg, int k,
                const float* __restrict__ H2, float* __restrict__ OUT,
                float* __restrict__ outacc, int* __restrict__ cur, int first) {
    __shared__ float ss[256];
    __shared__ int si_[256];
    __shared__ int rankOf[256];
    const int g = blockIdx.x;
    const int t = threadIdx.x;
    if (t < npg) { ss[t] = score[g * npg + t]; si_[t] = t; }
    else         { ss[t] = -INFINITY; si_[t] = 0x7FFFFFFF; }
    for (int size = 2; size <= 256; size <<= 1) {
        for (int stride = size >> 1; stride > 0; stride >>= 1) {
            __syncthreads();
            int i = t, j = t ^ stride;
            if (j > i) {
                float a = ss[i], b = ss[j];
                int ia = si_[i], ib = si_[j];
                bool inOrder = (a > b) || (a == b && ia < ib);
                bool desc = ((i & size) == 0);
                if (desc ? !inOrder : inOrder) {
                    ss[i] = b; ss[j] = a; si_[i] = ib; si_[j] = ia;
                }
            }
        }
    }
    __syncthreads();
    rankOf[t] = -1;
    __syncthreads();
    if (t < k) rankOf[si_[t]] = t;
    __syncthreads();
    {
        int v = g * 256 + t;
        int c = cur[v];
        cur[v] = (c >= 0) ? rankOf[c] : -1;
    }
    // pool + readout: n-ascending, 4-way unrolled (k % 4 == 0 always)
    const size_t gb = (size_t)g * npg * 256;
    float mx = -INFINITY, sm = 0.f;
    for (int n = 0; n < k; n += 4) {
        float v0 = H2[gb + (size_t)si_[n + 0] * 256 + t] * ss[n + 0];
        float v1 = H2[gb + (size_t)si_[n + 1] * 256 + t] * ss[n + 1];
        float v2 = H2[gb + (size_t)si_[n + 2] * 256 + t] * ss[n + 2];
        float v3 = H2[gb + (size_t)si_[n + 3] * 256 + t] * ss[n + 3];
        size_t ob = ((size_t)g * k + n) * 256 + t;
        OUT[ob]       = v0;
        OUT[ob + 256] = v1;
        OUT[ob + 512] = v2;
        OUT[ob + 768] = v3;
        mx = fmaxf(mx, v0); sm += v0;
        mx = fmaxf(mx, v1); sm += v1;
        mx = fmaxf(mx, v2); sm += v2;
        mx = fmaxf(mx, v3); sm += v3;
    }
    float mean = sm / (float)k;
    if (first) {
        outacc[g * 512 + t] = mx;
        outacc[g * 512 + 256 + t] = mean;
    } else {
        outacc[g * 512 + t] += mx;
        outacc[g * 512 + 256 + t] += mean;
    }
}

__global__ __launch_bounds__(256)
void mlp_head(const float* __restrict__ outacc,
              const float* __restrict__ l1w, const float* __restrict__ l1b,
              const float* __restrict__ l2w, const float* __restrict__ l2b,
              const float* __restrict__ l3w, const float* __restrict__ l3b,
              float* __restrict__ out) {
    __shared__ float row[512];
    __shared__ float h1[256];
    __shared__ float h2[128];
    const int g = blockIdx.x;
    const int t = threadIdx.x;
    row[t] = outacc[g * 512 + t];
    row[256 + t] = outacc[g * 512 + 256 + t];
    __syncthreads();
    {
        float a = l1b[t];
        for (int j = 0; j < 512; ++j) a += row[j] * l1w[j * 256 + t];
        h1[t] = fmaxf(a, 0.f);
    }
    __syncthreads();
    if (t < 128) {
        float a2 = l2b[t];
        for (int j = 0; j < 256; ++j) a2 += h1[j] * l2w[j * 128 + t];
        h2[t] = fmaxf(a2, 0.f);
    }
    __syncthreads();
    if (t == 0) {
        float l0 = l3b[0], l1 = l3b[1];
        for (int j = 0; j < 128; ++j) {
            float h = h2[j];
            l0 += h * l3w[j * 2 + 0];
            l1 += h * l3w[j * 2 + 1];
        }
        float m = fmaxf(l0, l1);
        float lse = m + logf(expf(l0 - m) + expf(l1 - m));
        out[g * 2 + 0] = l0 - lse;
        out[g * 2 + 1] = l1 - lse;
    }
}

// ============================================================================
// Fallback: proven R15 monolith (used only if ws_size is too small)
// ============================================================================
__global__ __launch_bounds__(256, 1)
void gnn_mono(const float* __restrict__ x, const int* __restrict__ ei,
              const float* __restrict__ gw0, const float* __restrict__ gb0,
              const float* __restrict__ gw1, const float* __restrict__ gb1,
              const float* __restrict__ gw2, const float* __restrict__ gb2,
              const float* __restrict__ pw0, const float* __restrict__ pw1,
              const float* __restrict__ pw2,
              const float* __restrict__ l1w, const float* __restrict__ l1b,
              const float* __restrict__ l2w, const float* __restrict__ l2b,
              const float* __restrict__ l3w, const float* __restrict__ l3b,
              float* __restrict__ out, float* __restrict__ ws) {
    const int g = blockIdx.x;
    const int t = threadIdx.x;
    float* P = ws + (size_t)g * HF * 256;
    float* Q = ws + (size_t)G_GRAPHS * HF * 256 + (size_t)g * HF * 256;
    __shared__ int   eb[EPG];
    __shared__ int   slots[EPG];
    __shared__ int   curID[256];
    __shared__ int   cntL[256];
    __shared__ int   startL[256];
    __shared__ float degF[256];
    __shared__ float dinv[256];
    __shared__ float sa[256];
    __shared__ float ss[256];
    __shared__ int   si_[256];
    __shared__ float scoreV[256];
    __shared__ int   kept[128];
    __shared__ int   rankOf[256];
    __shared__ float row[512];
    for (int e = t; e < EPG; e += 256) {
        size_t idx = (size_t)g * EPG + e;
        eb[e] = ((ei[idx] - g * 256) << 8) | (ei[E_TOT + idx] - g * 256);
    }
    curID[t] = t;
    float accMx = 0.f, accMn = 0.f;
    const float* GW[3] = {gw0, gw1, gw2};
    const float* GB[3] = {gb0, gb1, gb2};
    const float* PW[3] = {pw0, pw1, pw2};
    const int kk[3] = {128, 64, 32};
    int npg = 256;
    __syncthreads();
    for (int s = 0; s < 3; ++s) {
        const int knext = kk[s];
        {
            const float* Wp = GW[s];
            const int K = (s == 0) ? FIN : HF;
            for (int n = 0; n < npg; ++n) {
                if (s == 0) { if (t < FIN) sa[t] = x[(size_t)(g * 256 + n) * FIN + t]; }
                else sa[t] = P[(size_t)n * HF + t];
                __syncthreads();
                float a = 0.f;
                for (int k2 = 0; k2 < K; ++k2) a += sa[k2] * Wp[k2 * HF + t];
                Q[(size_t)n * HF + t] = a;
                __syncthreads();
            }
        }
        cntL[t] = 0;
        __syncthreads();
        for (int e = t; e < EPG; e += 256) {
            int p = eb[e];
            int cu = curID[p >> 8], cv = curID[p & 255];
            if (cu >= 0 && cv >= 0) atomicAdd(&cntL[cv], 1);
        }
        __syncthreads();
        if (t == 0) { int run = 0; for (int i = 0; i < npg; ++i) { startL[i] = run; run += cntL[i]; } }
        __syncthreads();
        if (t < npg) {
            float d = (float)cntL[t] + 1.0f;
            degF[t] = d;
            dinv[t] = 1.0f / sqrtf(d);
            int c = startL[t];
            for (int e = 0; e < EPG; ++e) {
                int p = eb[e];
                int cu = curID[p >> 8], cv = curID[p & 255];
                if (cu >= 0 && cv >= 0 && cv == t) slots[c++] = e;
            }
        }
        __syncthreads();
        {
            const float bb = GB[s][t];
            for (int n = 0; n < npg; ++n) {
                float acc = 0.f;
                const int s0 = startL[n], s1 = s0 + cntL[n];
                for (int j = s0; j < s1; ++j) {
                    int scur = curID[eb[slots[j]] >> 8];
                    acc += dinv[scur] * Q[(size_t)scur * HF + t];
                }
                float v = acc * dinv[n] + Q[(size_t)n * HF + t] / degF[n] + bb;
                P[(size_t)n * HF + t] = fmaxf(v, 0.f);
            }
        }
        __syncthreads();
        {
            const float* pwp = PW[s];
            const int lane = t & 63, wv = t >> 6;
            float s2p = 0.f;
            for (int j = 0; j < 4; ++j) { float w = pwp[lane + 64 * j]; s2p += w * w; }
            for (int off = 32; off; off >>= 1) s2p += __shfl_down(s2p, off, 64);
            s2p = __shfl(s2p, 0, 64);
            const float nw = sqrtf(s2p);
            for (int n = wv; n < npg; n += 4) {
                float pr = 0.f;
                for (int j = 0; j < 4; ++j) { int f = lane + 64 * j; pr += P[(size_t)n * HF + f] * pwp[f]; }
                for (int off = 32; off; off >>= 1) pr += __shfl_down(pr, off, 64);
                if (lane == 0) scoreV[n] = tanhf(pr / nw);
            }
        }
        __syncthreads();
        if (t < npg) { ss[t] = scoreV[t]; si_[t] = t; }
        else         { ss[t] = -INFINITY; si_[t] = 0x7FFFFFFF; }
        for (int size = 2; size <= 256; size <<= 1) {
            for (int stride = size >> 1; stride > 0; stride >>= 1) {
                __syncthreads();
                int i = t, j = t ^ stride;
                if (j > i) {
                    float a = ss[i], b = ss[j];
                    int ia = si_[i], ib = si_[j];
                    bool inOrder = (a > b) || (a == b && ia < ib);
                    bool desc = ((i & size) == 0);
                    if (desc ? !inOrder : inOrder) { ss[i] = b; ss[j] = a; si_[i] = ib; si_[j] = ia; }
                }
            }
        }
        __syncthreads();
        if (t < knext) kept[t] = si_[t];
        __syncthreads();
        {
            float mx = -INFINITY, sm = 0.f;
            for (int n = 0; n < knext; ++n) {
                int o = kept[n];
                float vv = P[(size_t)o * HF + t] * scoreV[o];
                Q[(size_t)n * HF + t] = vv;
                mx = fmaxf(mx, vv);
                sm += vv;
            }
            accMx += mx;
            accMn += sm / (float)knext;
        }
        rankOf[t] = -1;
        __syncthreads();
        if (t < knext) rankOf[kept[t]] = t;
        __syncthreads();
        { int c = curID[t]; curID[t] = (c >= 0) ? rankOf[c] : -1; }
        __syncthreads();
        { float* tmp = P; P = Q; Q = tmp; }
        npg = knext;
    }
    row[t] = accMx;
    row[256 + t] = accMn;
    __syncthreads();
    { float a = l1b[t]; for (int j = 0; j < 512; ++j) a += row[j] * l1w[j * 256 + t]; scoreV[t] = fmaxf(a, 0.f); }
    __syncthreads();
    if (t < 128) { float a2 = l2b[t]; for (int j = 0; j < 256; ++j) a2 += scoreV[j] * l2w[j * 128 + t]; sa[t] = fmaxf(a2, 0.f); }
    __syncthreads();
    if (t == 0) {
        float l0 = l3b[0], l1 = l3b[1];
        for (int j = 0; j < 128; ++j) { float h = sa[j]; l0 += h * l3w[j * 2 + 0]; l1 += h * l3w[j * 2 + 1]; }
        float m = fmaxf(l0, l1);
        float lse = m + logf(expf(l0 - m) + expf(l1 - m));
        out[g * 2 + 0] = l0 - lse;
        out[g * 2 + 1] = l1 - lse;
    }
}

// ============================================================================
extern "C" void kernel_launch(void* const* d_in, const int* in_sizes, int n_in,
                              void* d_out, int out_size, void* d_ws, size_t ws_size,
                              hipStream_t stream) {
    const float* x   = (const float*)d_in[0];
    const int*   ei  = (const int*)d_in[1];
    const float* gw0 = (const float*)d_in[3];
    const float* gb0 = (const float*)d_in[4];
    const float* gw1 = (const float*)d_in[5];
    const float* gb1 = (const float*)d_in[6];
    const float* gw2 = (const float*)d_in[7];
    const float* gb2 = (const float*)d_in[8];
    const float* pw0 = (const float*)d_in[9];
    const float* pw1 = (const float*)d_in[10];
    const float* pw2 = (const float*)d_in[11];
    const float* l1w = (const float*)d_in[12];
    const float* l1b = (const float*)d_in[13];
    const float* l2w = (const float*)d_in[14];
    const float* l2b = (const float*)d_in[15];
    const float* l3w = (const float*)d_in[16];
    const float* l3b = (const float*)d_in[17];
    float* out = (float*)d_out;

    const size_t SLAB = (size_t)65536 * 256;
    char* p = (char*)d_ws;
    float* P      = (float*)p; p += SLAB * 4;
    float* Q      = (float*)p; p += SLAB * 4;
    int*   cur    = (int*)p;   p += (size_t)65536 * 4;
    int*   degS   = (int*)p;   p += (size_t)65536 * 4;
    float* dinvS  = (float*)p; p += (size_t)65536 * 4;
    int*   starts = (int*)p;   p += (size_t)65536 * 4;
    int2*  slots2 = (int2*)p;  p += (size_t)E_TOT * 8;
    float* score  = (float*)p; p += (size_t)65536 * 4;
    int*   kept   = (int*)p;   p += (size_t)32768 * 4;
    float* outacc = (float*)p; p += (size_t)G_GRAPHS * 512 * 4;
    const size_t needed = (size_t)(p - (char*)d_ws);

    if (ws_size < needed) {
        gnn_mono<<<G_GRAPHS, 256, 0, stream>>>(
            x, ei, gw0, gb0, gw1, gb1, gw2, gb2, pw0, pw1, pw2,
            l1w, l1b, l2w, l2b, l3w, l3b, out, (float*)d_ws);
        return;
    }

    init_cur<<<(G_GRAPHS * 256 + 255) / 256, 256, 0, stream>>>(cur);

    const int   npg[3] = {256, 128, 64};
    const int   kk[3]  = {128, 64, 32};
    const int   Ns[3]  = {65536, 32768, 16384};
    const float* GW[3] = {gw0, gw1, gw2};
    const float* GB[3] = {gb0, gb1, gb2};
    const float* PW[3] = {pw0, pw1, pw2};

    float* HLs[3]   = {P, Q, P};
    float* H2s[3]   = {Q, P, Q};
    float* POOLs[3] = {P, Q, P};

    for (int s = 0; s < 3; ++s) {
        const int n = Ns[s];
        const int k = kk[s];
        // 1) GEMM v10: lane=row, scalar-W, A-only LDS (dbuf, 17KB)
        if (s == 0) {
            gemm_v10<FIN><<<dim3(n / 64, 2), 256, 0, stream>>>(x, GW[s], HLs[s]);
        } else {
            gemm_v10<HF><<<dim3(n / 64, 2), 256, 0, stream>>>(POOLs[s - 1], GW[s], HLs[s]);
        }
        // 2) CSR (parallel stable counting sort, packed slots)
        csr_build<<<G_GRAPHS, 256, 0, stream>>>(ei, cur, npg[s],
                                                degS, dinvS, starts, slots2);
        // 3) conv + score v2: wave-per-node, float4 gathers, no barriers
        agg_score2<<<n / 4, 256, 0, stream>>>(degS, dinvS, starts, slots2,
                                              HLs[s], H2s[s], GB[s], PW[s], score,
                                              n / 32);
        // 4-6) top-k + cur update + pool + readout, fused
        topk_fused<<<G_GRAPHS, 256, 0, stream>>>(score, npg[s], k,
                                                 H2s[s], POOLs[s], outacc, cur,
                                                 s == 0 ? 1 : 0);
    }

    mlp_head<<<G_GRAPHS, 256, 0, stream>>>(outacc, l1w, l1b, l2w, l2b, l3w, l3b, out);
}

// Round 8
// 444.023 us; speedup vs baseline: 1.1896x; 1.1896x over previous
//
#include <hip/hip_runtime.h>
#include <hip/hip_bf16.h>
#include <math.h>

#define G_GRAPHS 256
#define EPG 2048
#define E_TOT 524288
#define HF 256
#define FIN 128

// ---------------------------------------------------------------------------
// C[N x 256] = A[N x K] @ W[K x 256], fp32, k-ascending single-accumulator
// chains (bit-exact vs all previous versions).
// v8 (R5-proven BEST: 61.5us, VALUBusy 55%): 64x128 tile, 4x8/thread, BK=32,
// async-STAGE split (issue next tile's loads before compute), single LDS
// buffer 25.5KB. v5/v10 (W off the LDS pipe) both lost to load latency;
// v9 (dbuf 52KB) lost occupancy. Do not re-litigate without new counters.
// ---------------------------------------------------------------------------
template <int K>
__global__ __launch_bounds__(256, 4)
void gemm_v8(const float* __restrict__ A, const float* __restrict__ W,
             float* __restrict__ C) {
    __shared__ __align__(16) float As[32 * 68];
    __shared__ __align__(16) float Wa[32 * 68];
    __shared__ __align__(16) float Wb[32 * 68];
    const int tid = threadIdx.x;
    const int tx = tid & 15;    // col groups: c0 + tx*4, c0 + 64 + tx*4
    const int ty = tid >> 4;    // rows r0 + ty*4 .. +3
    const int r0 = blockIdx.x * 64;
    const int c0 = blockIdx.y * 128;
    const int l8 = tid >> 3;    // 0..31 (A staging row-within-slab)
    const int kq = tid & 7;     // A staging float4 index along k
    const int wkk = tid >> 5;   // 0..7  (W staging kk base)
    const int wc = tid & 31;    // W staging float4 col index
    float acc[4][8] = {{0.f}};
    float4 va0, va1, vw0, vw1, vw2, vw3;

    auto load_regs = [&](int k0) {
        va0 = *(const float4*)&A[(size_t)(r0 + l8) * K + k0 + 4 * kq];
        va1 = *(const float4*)&A[(size_t)(r0 + 32 + l8) * K + k0 + 4 * kq];
        vw0 = *(const float4*)&W[(size_t)(k0 + 0  + wkk) * 256 + c0 + 4 * wc];
        vw1 = *(const float4*)&W[(size_t)(k0 + 8  + wkk) * 256 + c0 + 4 * wc];
        vw2 = *(const float4*)&W[(size_t)(k0 + 16 + wkk) * 256 + c0 + 4 * wc];
        vw3 = *(const float4*)&W[(size_t)(k0 + 24 + wkk) * 256 + c0 + 4 * wc];
    };
    auto write_stage = [&]() {
        {
            int rs = l8 ^ (kq << 3);
            As[(4 * kq + 0) * 68 + rs] = va0.x;
            As[(4 * kq + 1) * 68 + rs] = va0.y;
            As[(4 * kq + 2) * 68 + rs] = va0.z;
            As[(4 * kq + 3) * 68 + rs] = va0.w;
        }
        {
            int rs = (32 + l8) ^ (kq << 3);
            As[(4 * kq + 0) * 68 + rs] = va1.x;
            As[(4 * kq + 1) * 68 + rs] = va1.y;
            As[(4 * kq + 2) * 68 + rs] = va1.z;
            As[(4 * kq + 3) * 68 + rs] = va1.w;
        }
        if (wc < 16) {
            *(float4*)&Wa[(0  + wkk) * 68 + 4 * wc] = vw0;
            *(float4*)&Wa[(8  + wkk) * 68 + 4 * wc] = vw1;
            *(float4*)&Wa[(16 + wkk) * 68 + 4 * wc] = vw2;
            *(float4*)&Wa[(24 + wkk) * 68 + 4 * wc] = vw3;
        } else {
            *(float4*)&Wb[(0  + wkk) * 68 + 4 * (wc - 16)] = vw0;
            *(float4*)&Wb[(8  + wkk) * 68 + 4 * (wc - 16)] = vw1;
            *(float4*)&Wb[(16 + wkk) * 68 + 4 * (wc - 16)] = vw2;
            *(float4*)&Wb[(24 + wkk) * 68 + 4 * (wc - 16)] = vw3;
        }
    };
    auto compute = [&]() {
#pragma unroll 4
        for (int kk = 0; kk < 32; ++kk) {
            const int g = (ty * 4) ^ ((kk >> 2) << 3);
            const float4 a0 = *(const float4*)&As[kk * 68 + g];
            const float4 w0 = *(const float4*)&Wa[kk * 68 + tx * 4];
            const float4 w1 = *(const float4*)&Wb[kk * 68 + tx * 4];
            float av[4] = {a0.x, a0.y, a0.z, a0.w};
            float wv_[8] = {w0.x, w0.y, w0.z, w0.w, w1.x, w1.y, w1.z, w1.w};
#pragma unroll
            for (int i = 0; i < 4; ++i)
#pragma unroll
                for (int j = 0; j < 8; ++j)
                    acc[i][j] += av[i] * wv_[j];
        }
    };

    load_regs(0);
    write_stage();
    __syncthreads();
    for (int k0 = 0; k0 < K - 32; k0 += 32) {
        load_regs(k0 + 32);   // issue early: in flight under compute
        compute();
        __syncthreads();      // all waves done reading this tile
        write_stage();        // vmcnt wait folded here (loads long returned)
        __syncthreads();
    }
    compute();                // last tile

#pragma unroll
    for (int i = 0; i < 4; ++i) {
        float4 v0 = make_float4(acc[i][0], acc[i][1], acc[i][2], acc[i][3]);
        float4 v1 = make_float4(acc[i][4], acc[i][5], acc[i][6], acc[i][7]);
        size_t base = (size_t)(r0 + ty * 4 + i) * 256 + c0 + tx * 4;
        *(float4*)&C[base] = v0;
        *(float4*)&C[base + 64] = v1;
    }
}

// ---------------------------------------------------------------------------
// CSR body (parallel stable counting sort, packed (src, dinv_src) slots).
// IDENT=true: cur is the identity mapping (stage 0). Shared arrays passed in.
// ---------------------------------------------------------------------------
template <bool IDENT>
__device__ __forceinline__ void csr_body(
    const int* __restrict__ ei, int g, int t, int npg, const int* curL,
    int* __restrict__ degS, float* __restrict__ dinvS,
    int* __restrict__ startsS, int2* __restrict__ slots2,
    int* cul, short* dstv, unsigned char* rnk, int (*h)[256],
    int* cnt, int* st) {
    const int lane = t & 63;
    const int wv = t >> 6;
    for (int i = t; i < 32 * 256; i += 256) ((int*)h)[i] = 0;
    for (int e = t; e < EPG; e += 256) {
        size_t idx = (size_t)g * EPG + e;
        int u = ei[idx] - g * 256;
        int v = ei[E_TOT + idx] - g * 256;
        int cu = IDENT ? u : curL[u];
        int cv = IDENT ? v : curL[v];
        bool valid = (cu >= 0 && cv >= 0);
        cul[e] = cu;
        dstv[e] = valid ? (short)cv : (short)256;
    }
    __syncthreads();
    for (int c = wv; c < 32; c += 4) {
        int e = c * 64 + lane;
        int d = (int)dstv[e];
        unsigned long long m = ~0ULL;
#pragma unroll
        for (int b = 0; b < 9; ++b) {
            unsigned long long bb = __ballot((d >> b) & 1);
            m &= ((d >> b) & 1) ? bb : ~bb;
        }
        int r = __popcll(m & ((1ULL << lane) - 1ULL));
        rnk[e] = (unsigned char)r;
        if (r == 0 && d < 256) h[c][d] = __popcll(m);
    }
    __syncthreads();
    if (t < npg) {
        int run = 0;
        for (int c = 0; c < 32; ++c) { int v = h[c][t]; h[c][t] = run; run += v; }
        cnt[t] = run;
        degS[g * npg + t] = run + 1;
        dinvS[g * npg + t] = 1.0f / sqrtf((float)(run + 1));
    }
    __syncthreads();
    if (t == 0) {
        int run = 0;
        for (int i = 0; i < npg; ++i) { st[i] = run; run += cnt[i]; }
    }
    __syncthreads();
    if (t < npg) startsS[g * npg + t] = g * EPG + st[t];
    for (int e = t; e < EPG; e += 256) {
        int d = (int)dstv[e];
        if (d < npg) {
            int slot = st[d] + h[e >> 6][d] + (int)rnk[e];
            int cu = cul[e];
            float dv = 1.0f / sqrtf((float)(cnt[cu] + 1));   // == dinvS[src]
            slots2[g * EPG + slot] = make_int2(g * npg + cu, __float_as_int(dv));
        }
    }
}

// ---------------------------------------------------------------------------
// init cur (identity) + CSR for stage 0, fused (same 256-block grid).
// ---------------------------------------------------------------------------
__global__ __launch_bounds__(256)
void fused_init_csr(const int* __restrict__ ei, int* __restrict__ cur,
                    int* __restrict__ degS, float* __restrict__ dinvS,
                    int* __restrict__ startsS, int2* __restrict__ slots2) {
    __shared__ int cul[EPG];
    __shared__ short dstv[EPG];
    __shared__ unsigned char rnk[EPG];
    __shared__ int h[32][256];
    __shared__ int cnt[256];
    __shared__ int st[256];
    const int g = blockIdx.x;
    const int t = threadIdx.x;
    cur[g * 256 + t] = t;
    csr_body<true>(ei, g, t, 256, nullptr, degS, dinvS, startsS, slots2,
                   cul, dstv, rnk, h, cnt, st);
}

// ---------------------------------------------------------------------------
// conv + relu + pool score, v2: ONE WAVE PER NODE, float4 per lane.
// (R2-proven: bit-exact.)
// ---------------------------------------------------------------------------
__global__ __launch_bounds__(256)
void agg_score2(const int* __restrict__ degS, const float* __restrict__ dinvS,
                const int* __restrict__ startsS, const int2* __restrict__ slots2,
                const float* __restrict__ HL, float* __restrict__ H2,
                const float* __restrict__ bias, const float* __restrict__ pw,
                float* __restrict__ score, int nbOver8) {
    __shared__ float vrow[4][256];
    const int t = threadIdx.x;
    const int wv = t >> 6;
    const int lane = t & 63;
    const int blk = (blockIdx.x & 7) * nbOver8 + (blockIdx.x >> 3);
    const int node = blk * 4 + wv;
    const int cntE = degS[node] - 1;
    const float degF = (float)(cntE + 1);
    const float dn = dinvS[node];
    const int2* sl = slots2 + startsS[node];
    float ax = 0.f, ay = 0.f, az = 0.f, aw = 0.f;
    int j = 0;
    for (; j + 8 <= cntE; j += 8) {
        int2 s[8];
#pragma unroll
        for (int u = 0; u < 8; ++u) s[u] = sl[j + u];
        float4 hv[8];
#pragma unroll
        for (int u = 0; u < 8; ++u)
            hv[u] = *(const float4*)&HL[(size_t)s[u].x * 256 + 4 * lane];
#pragma unroll
        for (int u = 0; u < 8; ++u) {
            float dv = __int_as_float(s[u].y);
            ax += dv * hv[u].x; ay += dv * hv[u].y;
            az += dv * hv[u].z; aw += dv * hv[u].w;
        }
    }
    for (; j + 4 <= cntE; j += 4) {
        int2 s[4];
#pragma unroll
        for (int u = 0; u < 4; ++u) s[u] = sl[j + u];
        float4 hv[4];
#pragma unroll
        for (int u = 0; u < 4; ++u)
            hv[u] = *(const float4*)&HL[(size_t)s[u].x * 256 + 4 * lane];
#pragma unroll
        for (int u = 0; u < 4; ++u) {
            float dv = __int_as_float(s[u].y);
            ax += dv * hv[u].x; ay += dv * hv[u].y;
            az += dv * hv[u].z; aw += dv * hv[u].w;
        }
    }
    for (; j < cntE; ++j) {
        int2 sv = sl[j];
        float dv = __int_as_float(sv.y);
        float4 hv = *(const float4*)&HL[(size_t)sv.x * 256 + 4 * lane];
        ax += dv * hv.x; ay += dv * hv.y; az += dv * hv.z; aw += dv * hv.w;
    }
    const float4 hn = *(const float4*)&HL[(size_t)node * 256 + 4 * lane];
    const float4 bi = *(const float4*)&bias[4 * lane];
    float4 v;
    v.x = ax * dn + hn.x / degF + bi.x;  v.x = fmaxf(v.x, 0.f);
    v.y = ay * dn + hn.y / degF + bi.y;  v.y = fmaxf(v.y, 0.f);
    v.z = az * dn + hn.z / degF + bi.z;  v.z = fmaxf(v.z, 0.f);
    v.w = aw * dn + hn.w / degF + bi.w;  v.w = fmaxf(v.w, 0.f);
    *(float4*)&H2[(size_t)node * 256 + 4 * lane] = v;
    *(float4*)&vrow[wv][4 * lane] = v;
    float pr = 0.f, s2p = 0.f;
    for (int jj = 0; jj < 4; ++jj) {
        int f = lane + 64 * jj;
        float w = pw[f];
        pr += vrow[wv][f] * w;
        s2p += w * w;
    }
    for (int off = 32; off; off >>= 1) {
        pr += __shfl_down(pr, off, 64);
        s2p += __shfl_down(s2p, off, 64);
    }
    s2p = __shfl(s2p, 0, 64);
    if (lane == 0) score[node] = tanhf(pr / sqrtf(s2p));
}

// ---------------------------------------------------------------------------
// topk(s) + cur update + pool + readout + CSR(s+1), fused. The CSR uses the
// just-updated cur held in LDS (saves a launch + the global cur round-trip).
// All accumulation chains identical to the unfused versions -> bit-exact.
// ---------------------------------------------------------------------------
__global__ __launch_bounds__(256)
void fused_topk_csr(const float* __restrict__ score, int npg, int k,
                    const float* __restrict__ H2, float* __restrict__ OUT,
                    float* __restrict__ outacc, int* __restrict__ cur, int first,
                    const int* __restrict__ ei,
                    int* __restrict__ degS, float* __restrict__ dinvS,
                    int* __restrict__ startsS, int2* __restrict__ slots2) {
    __shared__ float ss[256];
    __shared__ int si_[256];
    __shared__ int rankOf[256];
    __shared__ int curL[256];
    __shared__ int cul[EPG];
    __shared__ short dstv[EPG];
    __shared__ unsigned char rnk[EPG];
    __shared__ int h[32][256];
    __shared__ int cnt[256];
    __shared__ int st[256];
    const int g = blockIdx.x;
    const int t = threadIdx.x;
    if (t < npg) { ss[t] = score[g * npg + t]; si_[t] = t; }
    else         { ss[t] = -INFINITY; si_[t] = 0x7FFFFFFF; }
    for (int size = 2; size <= 256; size <<= 1) {
        for (int stride = size >> 1; stride > 0; stride >>= 1) {
            __syncthreads();
            int i = t, j = t ^ stride;
            if (j > i) {
                float a = ss[i], b = ss[j];
                int ia = si_[i], ib = si_[j];
                bool inOrder = (a > b) || (a == b && ia < ib);
                bool desc = ((i & size) == 0);
                if (desc ? !inOrder : inOrder) {
                    ss[i] = b; ss[j] = a; si_[i] = ib; si_[j] = ia;
                }
            }
        }
    }
    __syncthreads();
    rankOf[t] = -1;
    __syncthreads();
    if (t < k) rankOf[si_[t]] = t;
    __syncthreads();
    {
        int v = g * 256 + t;
        int c = cur[v];
        int nc = (c >= 0) ? rankOf[c] : -1;
        cur[v] = nc;
        curL[t] = nc;
    }
    // pool + readout: n-ascending, 4-way unrolled (k % 4 == 0 always)
    const size_t gb = (size_t)g * npg * 256;
    float mx = -INFINITY, sm = 0.f;
    for (int n = 0; n < k; n += 4) {
        float v0 = H2[gb + (size_t)si_[n + 0] * 256 + t] * ss[n + 0];
        float v1 = H2[gb + (size_t)si_[n + 1] * 256 + t] * ss[n + 1];
        float v2 = H2[gb + (size_t)si_[n + 2] * 256 + t] * ss[n + 2];
        float v3 = H2[gb + (size_t)si_[n + 3] * 256 + t] * ss[n + 3];
        size_t ob = ((size_t)g * k + n) * 256 + t;
        OUT[ob]       = v0;
        OUT[ob + 256] = v1;
        OUT[ob + 512] = v2;
        OUT[ob + 768] = v3;
        mx = fmaxf(mx, v0); sm += v0;
        mx = fmaxf(mx, v1); sm += v1;
        mx = fmaxf(mx, v2); sm += v2;
        mx = fmaxf(mx, v3); sm += v3;
    }
    float mean = sm / (float)k;
    if (first) {
        outacc[g * 512 + t] = mx;
        outacc[g * 512 + 256 + t] = mean;
    } else {
        outacc[g * 512 + t] += mx;
        outacc[g * 512 + 256 + t] += mean;
    }
    __syncthreads();   // curL visible to all before the CSR edge pass
    csr_body<false>(ei, g, t, k, curL, degS, dinvS, startsS, slots2,
                    cul, dstv, rnk, h, cnt, st);
}

// ---------------------------------------------------------------------------
// topk(2) + readout + MLP head, fused. No cur update / no OUT write needed
// after the last stage (POOL2 has no consumer). outacc chain preserved:
// row = (outacc_after_s1) + s2 contribution -- identical float order.
// ---------------------------------------------------------------------------
__global__ __launch_bounds__(256)
void fused_topk_mlp(const float* __restrict__ score, int npg, int k,
                    const float* __restrict__ H2,
                    const float* __restrict__ outacc,
                    const float* __restrict__ l1w, const float* __restrict__ l1b,
                    const float* __restrict__ l2w, const float* __restrict__ l2b,
                    const float* __restrict__ l3w, const float* __restrict__ l3b,
                    float* __restrict__ out) {
    __shared__ float ss[256];
    __shared__ int si_[256];
    __shared__ float row[512];
    __shared__ float h1[256];
    __shared__ float h2[128];
    const int g = blockIdx.x;
    const int t = threadIdx.x;
    if (t < npg) { ss[t] = score[g * npg + t]; si_[t] = t; }
    else         { ss[t] = -INFINITY; si_[t] = 0x7FFFFFFF; }
    for (int size = 2; size <= 256; size <<= 1) {
        for (int stride = size >> 1; stride > 0; stride >>= 1) {
            __syncthreads();
            int i = t, j = t ^ stride;
            if (j > i) {
                float a = ss[i], b = ss[j];
                int ia = si_[i], ib = si_[j];
                bool inOrder = (a > b) || (a == b && ia < ib);
                bool desc = ((i & size) == 0);
                if (desc ? !inOrder : inOrder) {
                    ss[i] = b; ss[j] = a; si_[i] = ib; si_[j] = ia;
                }
            }
        }
    }
    __syncthreads();
    const size_t gb = (size_t)g * npg * 256;
    float mx = -INFINITY, sm = 0.f;
    for (int n = 0; n < k; n += 4) {
        float v0 = H2[gb + (size_t)si_[n + 0] * 256 + t] * ss[n + 0];
        float v1 = H2[gb + (size_t)si_[n + 1] * 256 + t] * ss[n + 1];
        float v2 = H2[gb + (size_t)si_[n + 2] * 256 + t] * ss[n + 2];
        float v3 = H2[gb + (size_t)si_[n + 3] * 256 + t] * ss[n + 3];
        mx = fmaxf(mx, v0); sm += v0;
        mx = fmaxf(mx, v1); sm += v1;
        mx = fmaxf(mx, v2); sm += v2;
        mx = fmaxf(mx, v3); sm += v3;
    }
    float mean = sm / (float)k;
    row[t]       = outacc[g * 512 + t] + mx;
    row[256 + t] = outacc[g * 512 + 256 + t] + mean;
    __syncthreads();
    {
        float a = l1b[t];
        for (int j = 0; j < 512; ++j) a += row[j] * l1w[j * 256 + t];
        h1[t] = fmaxf(a, 0.f);
    }
    __syncthreads();
    if (t < 128) {
        float a2 = l2b[t];
        for (int j = 0; j < 256; ++j) a2 += h1[j] * l2w[j * 128 + t];
        h2[t] = fmaxf(a2, 0.f);
    }
    __syncthreads();
    if (t == 0) {
        float l0 = l3b[0], l1 = l3b[1];
        for (int j = 0; j < 128; ++j) {
            float h = h2[j];
            l0 += h * l3w[j * 2 + 0];
            l1 += h * l3w[j * 2 + 1];
        }
        float m = fmaxf(l0, l1);
        float lse = m + logf(expf(l0 - m) + expf(l1 - m));
        out[g * 2 + 0] = l0 - lse;
        out[g * 2 + 1] = l1 - lse;
    }
}

// ============================================================================
// Fallback: proven R15 monolith (used only if ws_size is too small)
// ============================================================================
__global__ __launch_bounds__(256, 1)
void gnn_mono(const float* __restrict__ x, const int* __restrict__ ei,
              const float* __restrict__ gw0, const float* __restrict__ gb0,
              const float* __restrict__ gw1, const float* __restrict__ gb1,
              const float* __restrict__ gw2, const float* __restrict__ gb2,
              const float* __restrict__ pw0, const float* __restrict__ pw1,
              const float* __restrict__ pw2,
              const float* __restrict__ l1w, const float* __restrict__ l1b,
              const float* __restrict__ l2w, const float* __restrict__ l2b,
              const float* __restrict__ l3w, const float* __restrict__ l3b,
              float* __restrict__ out, float* __restrict__ ws) {
    const int g = blockIdx.x;
    const int t = threadIdx.x;
    float* P = ws + (size_t)g * HF * 256;
    float* Q = ws + (size_t)G_GRAPHS * HF * 256 + (size_t)g * HF * 256;
    __shared__ int   eb[EPG];
    __shared__ int   slots[EPG];
    __shared__ int   curID[256];
    __shared__ int   cntL[256];
    __shared__ int   startL[256];
    __shared__ float degF[256];
    __shared__ float dinv[256];
    __shared__ float sa[256];
    __shared__ float ss[256];
    __shared__ int   si_[256];
    __shared__ float scoreV[256];
    __shared__ int   kept[128];
    __shared__ int   rankOf[256];
    __shared__ float row[512];
    for (int e = t; e < EPG; e += 256) {
        size_t idx = (size_t)g * EPG + e;
        eb[e] = ((ei[idx] - g * 256) << 8) | (ei[E_TOT + idx] - g * 256);
    }
    curID[t] = t;
    float accMx = 0.f, accMn = 0.f;
    const float* GW[3] = {gw0, gw1, gw2};
    const float* GB[3] = {gb0, gb1, gb2};
    const float* PW[3] = {pw0, pw1, pw2};
    const int kk[3] = {128, 64, 32};
    int npg = 256;
    __syncthreads();
    for (int s = 0; s < 3; ++s) {
        const int knext = kk[s];
        {
            const float* Wp = GW[s];
            const int K = (s == 0) ? FIN : HF;
            for (int n = 0; n < npg; ++n) {
                if (s == 0) { if (t < FIN) sa[t] = x[(size_t)(g * 256 + n) * FIN + t]; }
                else sa[t] = P[(size_t)n * HF + t];
                __syncthreads();
                float a = 0.f;
                for (int k2 = 0; k2 < K; ++k2) a += sa[k2] * Wp[k2 * HF + t];
                Q[(size_t)n * HF + t] = a;
                __syncthreads();
            }
        }
        cntL[t] = 0;
        __syncthreads();
        for (int e = t; e < EPG; e += 256) {
            int p = eb[e];
            int cu = curID[p >> 8], cv = curID[p & 255];
            if (cu >= 0 && cv >= 0) atomicAdd(&cntL[cv], 1);
        }
        __syncthreads();
        if (t == 0) { int run = 0; for (int i = 0; i < npg; ++i) { startL[i] = run; run += cntL[i]; } }
        __syncthreads();
        if (t < npg) {
            float d = (float)cntL[t] + 1.0f;
            degF[t] = d;
            dinv[t] = 1.0f / sqrtf(d);
            int c = startL[t];
            for (int e = 0; e < EPG; ++e) {
                int p = eb[e];
                int cu = curID[p >> 8], cv = curID[p & 255];
                if (cu >= 0 && cv >= 0 && cv == t) slots[c++] = e;
            }
        }
        __syncthreads();
        {
            const float bb = GB[s][t];
            for (int n = 0; n < npg; ++n) {
                float acc = 0.f;
                const int s0 = startL[n], s1 = s0 + cntL[n];
                for (int j = s0; j < s1; ++j) {
                    int scur = curID[eb[slots[j]] >> 8];
                    acc += dinv[scur] * Q[(size_t)scur * HF + t];
                }
                float v = acc * dinv[n] + Q[(size_t)n * HF + t] / degF[n] + bb;
                P[(size_t)n * HF + t] = fmaxf(v, 0.f);
            }
        }
        __syncthreads();
        {
            const float* pwp = PW[s];
            const int lane = t & 63, wv = t >> 6;
            float s2p = 0.f;
            for (int j = 0; j < 4; ++j) { float w = pwp[lane + 64 * j]; s2p += w * w; }
            for (int off = 32; off; off >>= 1) s2p += __shfl_down(s2p, off, 64);
            s2p = __shfl(s2p, 0, 64);
            const float nw = sqrtf(s2p);
            for (int n = wv; n < npg; n += 4) {
                float pr = 0.f;
                for (int j = 0; j < 4; ++j) { int f = lane + 64 * j; pr += P[(size_t)n * HF + f] * pwp[f]; }
                for (int off = 32; off; off >>= 1) pr += __shfl_down(pr, off, 64);
                if (lane == 0) scoreV[n] = tanhf(pr / nw);
            }
        }
        __syncthreads();
        if (t < npg) { ss[t] = scoreV[t]; si_[t] = t; }
        else         { ss[t] = -INFINITY; si_[t] = 0x7FFFFFFF; }
        for (int size = 2; size <= 256; size <<= 1) {
            for (int stride = size >> 1; stride > 0; stride >>= 1) {
                __syncthreads();
                int i = t, j = t ^ stride;
                if (j > i) {
                    float a = ss[i], b = ss[j];
                    int ia = si_[i], ib = si_[j];
                    bool inOrder = (a > b) || (a == b && ia < ib);
                    bool desc = ((i & size) == 0);
                    if (desc ? !inOrder : inOrder) { ss[i] = b; ss[j] = a; si_[i] = ib; si_[j] = ia; }
                }
            }
        }
        __syncthreads();
        if (t < knext) kept[t] = si_[t];
        __syncthreads();
        {
            float mx = -INFINITY, sm = 0.f;
            for (int n = 0; n < knext; ++n) {
                int o = kept[n];
                float vv = P[(size_t)o * HF + t] * scoreV[o];
                Q[(size_t)n * HF + t] = vv;
                mx = fmaxf(mx, vv);
                sm += vv;
            }
            accMx += mx;
            accMn += sm / (float)knext;
        }
        rankOf[t] = -1;
        __syncthreads();
        if (t < knext) rankOf[kept[t]] = t;
        __syncthreads();
        { int c = curID[t]; curID[t] = (c >= 0) ? rankOf[c] : -1; }
        __syncthreads();
        { float* tmp = P; P = Q; Q = tmp; }
        npg = knext;
    }
    row[t] = accMx;
    row[256 + t] = accMn;
    __syncthreads();
    { float a = l1b[t]; for (int j = 0; j < 512; ++j) a += row[j] * l1w[j * 256 + t]; scoreV[t] = fmaxf(a, 0.f); }
    __syncthreads();
    if (t < 128) { float a2 = l2b[t]; for (int j = 0; j < 256; ++j) a2 += scoreV[j] * l2w[j * 128 + t]; sa[t] = fmaxf(a2, 0.f); }
    __syncthreads();
    if (t == 0) {
        float l0 = l3b[0], l1 = l3b[1];
        for (int j = 0; j < 128; ++j) { float h = sa[j]; l0 += h * l3w[j * 2 + 0]; l1 += h * l3w[j * 2 + 1]; }
        float m = fmaxf(l0, l1);
        float lse = m + logf(expf(l0 - m) + expf(l1 - m));
        out[g * 2 + 0] = l0 - lse;
        out[g * 2 + 1] = l1 - lse;
    }
}

// ============================================================================
extern "C" void kernel_launch(void* const* d_in, const int* in_sizes, int n_in,
                              void* d_out, int out_size, void* d_ws, size_t ws_size,
                              hipStream_t stream) {
    const float* x   = (const float*)d_in[0];
    const int*   ei  = (const int*)d_in[1];
    const float* gw0 = (const float*)d_in[3];
    const float* gb0 = (const float*)d_in[4];
    const float* gw1 = (const float*)d_in[5];
    const float* gb1 = (const float*)d_in[6];
    const float* gw2 = (const float*)d_in[7];
    const float* gb2 = (const float*)d_in[8];
    const float* pw0 = (const float*)d_in[9];
    const float* pw1 = (const float*)d_in[10];
    const float* pw2 = (const float*)d_in[11];
    const float* l1w = (const float*)d_in[12];
    const float* l1b = (const float*)d_in[13];
    const float* l2w = (const float*)d_in[14];
    const float* l2b = (const float*)d_in[15];
    const float* l3w = (const float*)d_in[16];
    const float* l3b = (const float*)d_in[17];
    float* out = (float*)d_out;

    const size_t SLAB = (size_t)65536 * 256;
    char* p = (char*)d_ws;
    float* P      = (float*)p; p += SLAB * 4;
    float* Q      = (float*)p; p += SLAB * 4;
    int*   cur    = (int*)p;   p += (size_t)65536 * 4;
    int*   degS   = (int*)p;   p += (size_t)65536 * 4;
    float* dinvS  = (float*)p; p += (size_t)65536 * 4;
    int*   starts = (int*)p;   p += (size_t)65536 * 4;
    int2*  slots2 = (int2*)p;  p += (size_t)E_TOT * 8;
    float* score  = (float*)p; p += (size_t)65536 * 4;
    int*   kept   = (int*)p;   p += (size_t)32768 * 4;
    float* outacc = (float*)p; p += (size_t)G_GRAPHS * 512 * 4;
    const size_t needed = (size_t)(p - (char*)d_ws);

    if (ws_size < needed) {
        gnn_mono<<<G_GRAPHS, 256, 0, stream>>>(
            x, ei, gw0, gb0, gw1, gb1, gw2, gb2, pw0, pw1, pw2,
            l1w, l1b, l2w, l2b, l3w, l3b, out, (float*)d_ws);
        return;
    }

    const int   npg[3] = {256, 128, 64};
    const int   kk[3]  = {128, 64, 32};
    const int   Ns[3]  = {65536, 32768, 16384};
    const float* GW[3] = {gw0, gw1, gw2};
    const float* GB[3] = {gb0, gb1, gb2};
    const float* PW[3] = {pw0, pw1, pw2};

    float* HLs[3]   = {P, Q, P};
    float* H2s[3]   = {Q, P, Q};
    float* POOLs[3] = {P, Q, P};

    // init cur + CSR(0), fused
    fused_init_csr<<<G_GRAPHS, 256, 0, stream>>>(ei, cur, degS, dinvS,
                                                 starts, slots2);

    for (int s = 0; s < 3; ++s) {
        const int n = Ns[s];
        const int k = kk[s];
        // 1) GEMM v8 (R5-proven best)
        if (s == 0) {
            gemm_v8<FIN><<<dim3(n / 64, 2), 256, 0, stream>>>(x, GW[s], HLs[s]);
        } else {
            gemm_v8<HF><<<dim3(n / 64, 2), 256, 0, stream>>>(POOLs[s - 1], GW[s], HLs[s]);
        }
        // 2) conv + score (wave-per-node, float4 gathers)
        agg_score2<<<n / 4, 256, 0, stream>>>(degS, dinvS, starts, slots2,
                                              HLs[s], H2s[s], GB[s], PW[s], score,
                                              n / 32);
        // 3) topk + pool + readout (+ CSR of next stage, or MLP at the end)
        if (s < 2) {
            fused_topk_csr<<<G_GRAPHS, 256, 0, stream>>>(
                score, npg[s], k, H2s[s], POOLs[s], outacc, cur, s == 0 ? 1 : 0,
                ei, degS, dinvS, starts, slots2);
        } else {
            fused_topk_mlp<<<G_GRAPHS, 256, 0, stream>>>(
                score, npg[s], k, H2s[s], outacc,
                l1w, l1b, l2w, l2b, l3w, l3b, out);
        }
    }
}

// Round 9
// 421.246 us; speedup vs baseline: 1.2539x; 1.0541x over previous
//
#include <hip/hip_runtime.h>
#include <hip/hip_bf16.h>
#include <math.h>

#define G_GRAPHS 256
#define EPG 2048
#define E_TOT 524288
#define HF 256
#define FIN 128

// ---------------------------------------------------------------------------
// GEMM model (R8-validated): time = LDS-pipe cycles = waves/CU x kk x reads x
// 12cy. Ratio LDS/FMA = 6*(RM+CN)/(RM*CN). v8 (4x8) = 2.25 -> 61.4us (==
// measured 61.5). v12 (8x8) = 1.5 -> 41us, needs BK=16 to keep VGPR<=128
// and LDS 17KB. v5/v10 (W from global) fail on latency: W must be staged.
// ---------------------------------------------------------------------------

// v8: 64x128 tile, 4x8/thread, BK=32 (R5-proven; used for s2 where v12's
// grid would be 1 block/CU).
template <int K>
__global__ __launch_bounds__(256, 4)
void gemm_v8(const float* __restrict__ A, const float* __restrict__ W,
             float* __restrict__ C) {
    __shared__ __align__(16) float As[32 * 68];
    __shared__ __align__(16) float Wa[32 * 68];
    __shared__ __align__(16) float Wb[32 * 68];
    const int tid = threadIdx.x;
    const int tx = tid & 15;
    const int ty = tid >> 4;
    const int r0 = blockIdx.x * 64;
    const int c0 = blockIdx.y * 128;
    const int l8 = tid >> 3;
    const int kq = tid & 7;
    const int wkk = tid >> 5;
    const int wc = tid & 31;
    float acc[4][8] = {{0.f}};
    float4 va0, va1, vw0, vw1, vw2, vw3;

    auto load_regs = [&](int k0) {
        va0 = *(const float4*)&A[(size_t)(r0 + l8) * K + k0 + 4 * kq];
        va1 = *(const float4*)&A[(size_t)(r0 + 32 + l8) * K + k0 + 4 * kq];
        vw0 = *(const float4*)&W[(size_t)(k0 + 0  + wkk) * 256 + c0 + 4 * wc];
        vw1 = *(const float4*)&W[(size_t)(k0 + 8  + wkk) * 256 + c0 + 4 * wc];
        vw2 = *(const float4*)&W[(size_t)(k0 + 16 + wkk) * 256 + c0 + 4 * wc];
        vw3 = *(const float4*)&W[(size_t)(k0 + 24 + wkk) * 256 + c0 + 4 * wc];
    };
    auto write_stage = [&]() {
        {
            int rs = l8 ^ (kq << 3);
            As[(4 * kq + 0) * 68 + rs] = va0.x;
            As[(4 * kq + 1) * 68 + rs] = va0.y;
            As[(4 * kq + 2) * 68 + rs] = va0.z;
            As[(4 * kq + 3) * 68 + rs] = va0.w;
        }
        {
            int rs = (32 + l8) ^ (kq << 3);
            As[(4 * kq + 0) * 68 + rs] = va1.x;
            As[(4 * kq + 1) * 68 + rs] = va1.y;
            As[(4 * kq + 2) * 68 + rs] = va1.z;
            As[(4 * kq + 3) * 68 + rs] = va1.w;
        }
        if (wc < 16) {
            *(float4*)&Wa[(0  + wkk) * 68 + 4 * wc] = vw0;
            *(float4*)&Wa[(8  + wkk) * 68 + 4 * wc] = vw1;
            *(float4*)&Wa[(16 + wkk) * 68 + 4 * wc] = vw2;
            *(float4*)&Wa[(24 + wkk) * 68 + 4 * wc] = vw3;
        } else {
            *(float4*)&Wb[(0  + wkk) * 68 + 4 * (wc - 16)] = vw0;
            *(float4*)&Wb[(8  + wkk) * 68 + 4 * (wc - 16)] = vw1;
            *(float4*)&Wb[(16 + wkk) * 68 + 4 * (wc - 16)] = vw2;
            *(float4*)&Wb[(24 + wkk) * 68 + 4 * (wc - 16)] = vw3;
        }
    };
    auto compute = [&]() {
#pragma unroll 4
        for (int kk = 0; kk < 32; ++kk) {
            const int g = (ty * 4) ^ ((kk >> 2) << 3);
            const float4 a0 = *(const float4*)&As[kk * 68 + g];
            const float4 w0 = *(const float4*)&Wa[kk * 68 + tx * 4];
            const float4 w1 = *(const float4*)&Wb[kk * 68 + tx * 4];
            float av[4] = {a0.x, a0.y, a0.z, a0.w};
            float wv_[8] = {w0.x, w0.y, w0.z, w0.w, w1.x, w1.y, w1.z, w1.w};
#pragma unroll
            for (int i = 0; i < 4; ++i)
#pragma unroll
                for (int j = 0; j < 8; ++j)
                    acc[i][j] += av[i] * wv_[j];
        }
    };

    load_regs(0);
    write_stage();
    __syncthreads();
    for (int k0 = 0; k0 < K - 32; k0 += 32) {
        load_regs(k0 + 32);
        compute();
        __syncthreads();
        write_stage();
        __syncthreads();
    }
    compute();

#pragma unroll
    for (int i = 0; i < 4; ++i) {
        float4 v0 = make_float4(acc[i][0], acc[i][1], acc[i][2], acc[i][3]);
        float4 v1 = make_float4(acc[i][4], acc[i][5], acc[i][6], acc[i][7]);
        size_t base = (size_t)(r0 + ty * 4 + i) * 256 + c0 + tx * 4;
        *(float4*)&C[base] = v0;
        *(float4*)&C[base + 64] = v1;
    }
}

// ---------------------------------------------------------------------------
// v12: 128x128 tile, 8x8/thread, BK=16, async staging (v8 ordering).
// LDS ratio 1.5 -> 41us bound. LDS 17KB; staging regs 16; acc 64 -> ~116 VGPR.
// Layouts: A transposed As[kk][row ^ (kq<<3)] stride 132 (v6-proven);
// W split halves Wa/Wb[16][68] (v3-proven). Bank math: staging 2-way free,
// compute reads broadcast/2-way free.
// ---------------------------------------------------------------------------
template <int K>
__global__ __launch_bounds__(256, 4)
void gemm_v12(const float* __restrict__ A, const float* __restrict__ W,
              float* __restrict__ C) {
    __shared__ __align__(16) float As[16 * 132];
    __shared__ __align__(16) float Wa[16 * 68];
    __shared__ __align__(16) float Wb[16 * 68];
    const int tid = threadIdx.x;
    const int tx = tid & 15;     // col groups: c0 + tx*4, c0 + 64 + tx*4
    const int ty = tid >> 4;     // rows r0 + ty*8 .. +7
    const int r0 = blockIdx.x * 128;
    const int c0 = blockIdx.y * 128;
    const int sr = tid >> 1;     // A staging row 0..127
    const int sq = tid & 1;      // A staging quad base: quads sq and sq+2
    const int wkk = tid >> 5;    // W staging kk 0..7 (and +8)
    const int wc = tid & 31;     // W staging float4 col index
    float acc[8][8] = {{0.f}};
    float4 va0, va1, vw0, vw1;

    auto load_regs = [&](int k0) {
        va0 = *(const float4*)&A[(size_t)(r0 + sr) * K + k0 + 4 * sq];
        va1 = *(const float4*)&A[(size_t)(r0 + sr) * K + k0 + 8 + 4 * sq];
        vw0 = *(const float4*)&W[(size_t)(k0 + wkk) * 256 + c0 + 4 * wc];
        vw1 = *(const float4*)&W[(size_t)(k0 + 8 + wkk) * 256 + c0 + 4 * wc];
    };
    auto write_stage = [&]() {
        {   // quad sq: banks (4u + sr)%32 / (16+4u+(sr^8))%32 -> 2-way free
            int rs = sr ^ (sq << 3);
            As[(4 * sq + 0) * 132 + rs] = va0.x;
            As[(4 * sq + 1) * 132 + rs] = va0.y;
            As[(4 * sq + 2) * 132 + rs] = va0.z;
            As[(4 * sq + 3) * 132 + rs] = va0.w;
        }
        {   // quad sq+2
            int kq = sq + 2;
            int rs = sr ^ (kq << 3);
            As[(4 * kq + 0) * 132 + rs] = va1.x;
            As[(4 * kq + 1) * 132 + rs] = va1.y;
            As[(4 * kq + 2) * 132 + rs] = va1.z;
            As[(4 * kq + 3) * 132 + rs] = va1.w;
        }
        if (wc < 16) {
            *(float4*)&Wa[wkk * 68 + 4 * wc] = vw0;
            *(float4*)&Wa[(8 + wkk) * 68 + 4 * wc] = vw1;
        } else {
            *(float4*)&Wb[wkk * 68 + 4 * (wc - 16)] = vw0;
            *(float4*)&Wb[(8 + wkk) * 68 + 4 * (wc - 16)] = vw1;
        }
    };
    auto compute = [&]() {
#pragma unroll 4
        for (int kk = 0; kk < 16; ++kk) {
            const int g = (ty ^ (kk >> 2)) << 3;   // row-block XOR unswizzle
            const float4 a0 = *(const float4*)&As[kk * 132 + g];
            const float4 a1 = *(const float4*)&As[kk * 132 + g + 4];
            const float4 w0 = *(const float4*)&Wa[kk * 68 + tx * 4];
            const float4 w1 = *(const float4*)&Wb[kk * 68 + tx * 4];
            float av[8] = {a0.x, a0.y, a0.z, a0.w, a1.x, a1.y, a1.z, a1.w};
            float wv_[8] = {w0.x, w0.y, w0.z, w0.w, w1.x, w1.y, w1.z, w1.w};
#pragma unroll
            for (int i = 0; i < 8; ++i)
#pragma unroll
                for (int j = 0; j < 8; ++j)
                    acc[i][j] += av[i] * wv_[j];
        }
    };

    load_regs(0);
    write_stage();
    __syncthreads();
    for (int k0 = 0; k0 < K - 16; k0 += 16) {
        load_regs(k0 + 16);   // issue early: in flight under compute
        compute();
        __syncthreads();      // all waves done reading this tile
        write_stage();
        __syncthreads();
    }
    compute();

#pragma unroll
    for (int i = 0; i < 8; ++i) {
        float4 v0 = make_float4(acc[i][0], acc[i][1], acc[i][2], acc[i][3]);
        float4 v1 = make_float4(acc[i][4], acc[i][5], acc[i][6], acc[i][7]);
        size_t base = (size_t)(r0 + ty * 8 + i) * 256 + c0 + tx * 4;
        *(float4*)&C[base] = v0;
        *(float4*)&C[base + 64] = v1;
    }
}

// ---------------------------------------------------------------------------
// CSR body (parallel stable counting sort, packed (src, dinv_src) slots).
// ---------------------------------------------------------------------------
template <bool IDENT>
__device__ __forceinline__ void csr_body(
    const int* __restrict__ ei, int g, int t, int npg, const int* curL,
    int* __restrict__ degS, float* __restrict__ dinvS,
    int* __restrict__ startsS, int2* __restrict__ slots2,
    int* cul, short* dstv, unsigned char* rnk, int (*h)[256],
    int* cnt, int* st) {
    const int lane = t & 63;
    const int wv = t >> 6;
    for (int i = t; i < 32 * 256; i += 256) ((int*)h)[i] = 0;
    for (int e = t; e < EPG; e += 256) {
        size_t idx = (size_t)g * EPG + e;
        int u = ei[idx] - g * 256;
        int v = ei[E_TOT + idx] - g * 256;
        int cu = IDENT ? u : curL[u];
        int cv = IDENT ? v : curL[v];
        bool valid = (cu >= 0 && cv >= 0);
        cul[e] = cu;
        dstv[e] = valid ? (short)cv : (short)256;
    }
    __syncthreads();
    for (int c = wv; c < 32; c += 4) {
        int e = c * 64 + lane;
        int d = (int)dstv[e];
        unsigned long long m = ~0ULL;
#pragma unroll
        for (int b = 0; b < 9; ++b) {
            unsigned long long bb = __ballot((d >> b) & 1);
            m &= ((d >> b) & 1) ? bb : ~bb;
        }
        int r = __popcll(m & ((1ULL << lane) - 1ULL));
        rnk[e] = (unsigned char)r;
        if (r == 0 && d < 256) h[c][d] = __popcll(m);
    }
    __syncthreads();
    if (t < npg) {
        int run = 0;
        for (int c = 0; c < 32; ++c) { int v = h[c][t]; h[c][t] = run; run += v; }
        cnt[t] = run;
        degS[g * npg + t] = run + 1;
        dinvS[g * npg + t] = 1.0f / sqrtf((float)(run + 1));
    }
    __syncthreads();
    if (t == 0) {
        int run = 0;
        for (int i = 0; i < npg; ++i) { st[i] = run; run += cnt[i]; }
    }
    __syncthreads();
    if (t < npg) startsS[g * npg + t] = g * EPG + st[t];
    for (int e = t; e < EPG; e += 256) {
        int d = (int)dstv[e];
        if (d < npg) {
            int slot = st[d] + h[e >> 6][d] + (int)rnk[e];
            int cu = cul[e];
            float dv = 1.0f / sqrtf((float)(cnt[cu] + 1));   // == dinvS[src]
            slots2[g * EPG + slot] = make_int2(g * npg + cu, __float_as_int(dv));
        }
    }
}

// ---------------------------------------------------------------------------
__global__ __launch_bounds__(256)
void fused_init_csr(const int* __restrict__ ei, int* __restrict__ cur,
                    int* __restrict__ degS, float* __restrict__ dinvS,
                    int* __restrict__ startsS, int2* __restrict__ slots2) {
    __shared__ int cul[EPG];
    __shared__ short dstv[EPG];
    __shared__ unsigned char rnk[EPG];
    __shared__ int h[32][256];
    __shared__ int cnt[256];
    __shared__ int st[256];
    const int g = blockIdx.x;
    const int t = threadIdx.x;
    cur[g * 256 + t] = t;
    csr_body<true>(ei, g, t, 256, nullptr, degS, dinvS, startsS, slots2,
                   cul, dstv, rnk, h, cnt, st);
}

// ---------------------------------------------------------------------------
// conv + relu + pool score (R2-proven wave-per-node, float4 per lane).
// ---------------------------------------------------------------------------
__global__ __launch_bounds__(256)
void agg_score2(const int* __restrict__ degS, const float* __restrict__ dinvS,
                const int* __restrict__ startsS, const int2* __restrict__ slots2,
                const float* __restrict__ HL, float* __restrict__ H2,
                const float* __restrict__ bias, const float* __restrict__ pw,
                float* __restrict__ score, int nbOver8) {
    __shared__ float vrow[4][256];
    const int t = threadIdx.x;
    const int wv = t >> 6;
    const int lane = t & 63;
    const int blk = (blockIdx.x & 7) * nbOver8 + (blockIdx.x >> 3);
    const int node = blk * 4 + wv;
    const int cntE = degS[node] - 1;
    const float degF = (float)(cntE + 1);
    const float dn = dinvS[node];
    const int2* sl = slots2 + startsS[node];
    float ax = 0.f, ay = 0.f, az = 0.f, aw = 0.f;
    int j = 0;
    for (; j + 8 <= cntE; j += 8) {
        int2 s[8];
#pragma unroll
        for (int u = 0; u < 8; ++u) s[u] = sl[j + u];
        float4 hv[8];
#pragma unroll
        for (int u = 0; u < 8; ++u)
            hv[u] = *(const float4*)&HL[(size_t)s[u].x * 256 + 4 * lane];
#pragma unroll
        for (int u = 0; u < 8; ++u) {
            float dv = __int_as_float(s[u].y);
            ax += dv * hv[u].x; ay += dv * hv[u].y;
            az += dv * hv[u].z; aw += dv * hv[u].w;
        }
    }
    for (; j + 4 <= cntE; j += 4) {
        int2 s[4];
#pragma unroll
        for (int u = 0; u < 4; ++u) s[u] = sl[j + u];
        float4 hv[4];
#pragma unroll
        for (int u = 0; u < 4; ++u)
            hv[u] = *(const float4*)&HL[(size_t)s[u].x * 256 + 4 * lane];
#pragma unroll
        for (int u = 0; u < 4; ++u) {
            float dv = __int_as_float(s[u].y);
            ax += dv * hv[u].x; ay += dv * hv[u].y;
            az += dv * hv[u].z; aw += dv * hv[u].w;
        }
    }
    for (; j < cntE; ++j) {
        int2 sv = sl[j];
        float dv = __int_as_float(sv.y);
        float4 hv = *(const float4*)&HL[(size_t)sv.x * 256 + 4 * lane];
        ax += dv * hv.x; ay += dv * hv.y; az += dv * hv.z; aw += dv * hv.w;
    }
    const float4 hn = *(const float4*)&HL[(size_t)node * 256 + 4 * lane];
    const float4 bi = *(const float4*)&bias[4 * lane];
    float4 v;
    v.x = ax * dn + hn.x / degF + bi.x;  v.x = fmaxf(v.x, 0.f);
    v.y = ay * dn + hn.y / degF + bi.y;  v.y = fmaxf(v.y, 0.f);
    v.z = az * dn + hn.z / degF + bi.z;  v.z = fmaxf(v.z, 0.f);
    v.w = aw * dn + hn.w / degF + bi.w;  v.w = fmaxf(v.w, 0.f);
    *(float4*)&H2[(size_t)node * 256 + 4 * lane] = v;
    *(float4*)&vrow[wv][4 * lane] = v;
    float pr = 0.f, s2p = 0.f;
    for (int jj = 0; jj < 4; ++jj) {
        int f = lane + 64 * jj;
        float w = pw[f];
        pr += vrow[wv][f] * w;
        s2p += w * w;
    }
    for (int off = 32; off; off >>= 1) {
        pr += __shfl_down(pr, off, 64);
        s2p += __shfl_down(s2p, off, 64);
    }
    s2p = __shfl(s2p, 0, 64);
    if (lane == 0) score[node] = tanhf(pr / sqrtf(s2p));
}

// ---------------------------------------------------------------------------
// topk(s) + cur update + pool + readout + CSR(s+1), fused (R8-proven).
// ---------------------------------------------------------------------------
__global__ __launch_bounds__(256)
void fused_topk_csr(const float* __restrict__ score, int npg, int k,
                    const float* __restrict__ H2, float* __restrict__ OUT,
                    float* __restrict__ outacc, int* __restrict__ cur, int first,
                    const int* __restrict__ ei,
                    int* __restrict__ degS, float* __restrict__ dinvS,
                    int* __restrict__ startsS, int2* __restrict__ slots2) {
    __shared__ float ss[256];
    __shared__ int si_[256];
    __shared__ int rankOf[256];
    __shared__ int curL[256];
    __shared__ int cul[EPG];
    __shared__ short dstv[EPG];
    __shared__ unsigned char rnk[EPG];
    __shared__ int h[32][256];
    __shared__ int cnt[256];
    __shared__ int st[256];
    const int g = blockIdx.x;
    const int t = threadIdx.x;
    if (t < npg) { ss[t] = score[g * npg + t]; si_[t] = t; }
    else         { ss[t] = -INFINITY; si_[t] = 0x7FFFFFFF; }
    for (int size = 2; size <= 256; size <<= 1) {
        for (int stride = size >> 1; stride > 0; stride >>= 1) {
            __syncthreads();
            int i = t, j = t ^ stride;
            if (j > i) {
                float a = ss[i], b = ss[j];
                int ia = si_[i], ib = si_[j];
                bool inOrder = (a > b) || (a == b && ia < ib);
                bool desc = ((i & size) == 0);
                if (desc ? !inOrder : inOrder) {
                    ss[i] = b; ss[j] = a; si_[i] = ib; si_[j] = ia;
                }
            }
        }
    }
    __syncthreads();
    rankOf[t] = -1;
    __syncthreads();
    if (t < k) rankOf[si_[t]] = t;
    __syncthreads();
    {
        int v = g * 256 + t;
        int c = cur[v];
        int nc = (c >= 0) ? rankOf[c] : -1;
        cur[v] = nc;
        curL[t] = nc;
    }
    const size_t gb = (size_t)g * npg * 256;
    float mx = -INFINITY, sm = 0.f;
    for (int n = 0; n < k; n += 4) {
        float v0 = H2[gb + (size_t)si_[n + 0] * 256 + t] * ss[n + 0];
        float v1 = H2[gb + (size_t)si_[n + 1] * 256 + t] * ss[n + 1];
        float v2 = H2[gb + (size_t)si_[n + 2] * 256 + t] * ss[n + 2];
        float v3 = H2[gb + (size_t)si_[n + 3] * 256 + t] * ss[n + 3];
        size_t ob = ((size_t)g * k + n) * 256 + t;
        OUT[ob]       = v0;
        OUT[ob + 256] = v1;
        OUT[ob + 512] = v2;
        OUT[ob + 768] = v3;
        mx = fmaxf(mx, v0); sm += v0;
        mx = fmaxf(mx, v1); sm += v1;
        mx = fmaxf(mx, v2); sm += v2;
        mx = fmaxf(mx, v3); sm += v3;
    }
    float mean = sm / (float)k;
    if (first) {
        outacc[g * 512 + t] = mx;
        outacc[g * 512 + 256 + t] = mean;
    } else {
        outacc[g * 512 + t] += mx;
        outacc[g * 512 + 256 + t] += mean;
    }
    __syncthreads();
    csr_body<false>(ei, g, t, k, curL, degS, dinvS, startsS, slots2,
                    cul, dstv, rnk, h, cnt, st);
}

// ---------------------------------------------------------------------------
// topk(2) + readout + MLP head, fused (R8-proven).
// ---------------------------------------------------------------------------
__global__ __launch_bounds__(256)
void fused_topk_mlp(const float* __restrict__ score, int npg, int k,
                    const float* __restrict__ H2,
                    const float* __restrict__ outacc,
                    const float* __restrict__ l1w, const float* __restrict__ l1b,
                    const float* __restrict__ l2w, const float* __restrict__ l2b,
                    const float* __restrict__ l3w, const float* __restrict__ l3b,
                    float* __restrict__ out) {
    __shared__ float ss[256];
    __shared__ int si_[256];
    __shared__ float row[512];
    __shared__ float h1[256];
    __shared__ float h2[128];
    const int g = blockIdx.x;
    const int t = threadIdx.x;
    if (t < npg) { ss[t] = score[g * npg + t]; si_[t] = t; }
    else         { ss[t] = -INFINITY; si_[t] = 0x7FFFFFFF; }
    for (int size = 2; size <= 256; size <<= 1) {
        for (int stride = size >> 1; stride > 0; stride >>= 1) {
            __syncthreads();
            int i = t, j = t ^ stride;
            if (j > i) {
                float a = ss[i], b = ss[j];
                int ia = si_[i], ib = si_[j];
                bool inOrder = (a > b) || (a == b && ia < ib);
                bool desc = ((i & size) == 0);
                if (desc ? !inOrder : inOrder) {
                    ss[i] = b; ss[j] = a; si_[i] = ib; si_[j] = ia;
                }
            }
        }
    }
    __syncthreads();
    const size_t gb = (size_t)g * npg * 256;
    float mx = -INFINITY, sm = 0.f;
    for (int n = 0; n < k; n += 4) {
        float v0 = H2[gb + (size_t)si_[n + 0] * 256 + t] * ss[n + 0];
        float v1 = H2[gb + (size_t)si_[n + 1] * 256 + t] * ss[n + 1];
        float v2 = H2[gb + (size_t)si_[n + 2] * 256 + t] * ss[n + 2];
        float v3 = H2[gb + (size_t)si_[n + 3] * 256 + t] * ss[n + 3];
        mx = fmaxf(mx, v0); sm += v0;
        mx = fmaxf(mx, v1); sm += v1;
        mx = fmaxf(mx, v2); sm += v2;
        mx = fmaxf(mx, v3); sm += v3;
    }
    float mean = sm / (float)k;
    row[t]       = outacc[g * 512 + t] + mx;
    row[256 + t] = outacc[g * 512 + 256 + t] + mean;
    __syncthreads();
    {
        float a = l1b[t];
        for (int j = 0; j < 512; ++j) a += row[j] * l1w[j * 256 + t];
        h1[t] = fmaxf(a, 0.f);
    }
    __syncthreads();
    if (t < 128) {
        float a2 = l2b[t];
        for (int j = 0; j < 256; ++j) a2 += h1[j] * l2w[j * 128 + t];
        h2[t] = fmaxf(a2, 0.f);
    }
    __syncthreads();
    if (t == 0) {
        float l0 = l3b[0], l1 = l3b[1];
        for (int j = 0; j < 128; ++j) {
            float h = h2[j];
            l0 += h * l3w[j * 2 + 0];
            l1 += h * l3w[j * 2 + 1];
        }
        float m = fmaxf(l0, l1);
        float lse = m + logf(expf(l0 - m) + expf(l1 - m));
        out[g * 2 + 0] = l0 - lse;
        out[g * 2 + 1] = l1 - lse;
    }
}

// ============================================================================
// Fallback: proven R15 monolith (used only if ws_size is too small)
// ============================================================================
__global__ __launch_bounds__(256, 1)
void gnn_mono(const float* __restrict__ x, const int* __restrict__ ei,
              const float* __restrict__ gw0, const float* __restrict__ gb0,
              const float* __restrict__ gw1, const float* __restrict__ gb1,
              const float* __restrict__ gw2, const float* __restrict__ gb2,
              const float* __restrict__ pw0, const float* __restrict__ pw1,
              const float* __restrict__ pw2,
              const float* __restrict__ l1w, const float* __restrict__ l1b,
              const float* __restrict__ l2w, const float* __restrict__ l2b,
              const float* __restrict__ l3w, const float* __restrict__ l3b,
              float* __restrict__ out, float* __restrict__ ws) {
    const int g = blockIdx.x;
    const int t = threadIdx.x;
    float* P = ws + (size_t)g * HF * 256;
    float* Q = ws + (size_t)G_GRAPHS * HF * 256 + (size_t)g * HF * 256;
    __shared__ int   eb[EPG];
    __shared__ int   slots[EPG];
    __shared__ int   curID[256];
    __shared__ int   cntL[256];
    __shared__ int   startL[256];
    __shared__ float degF[256];
    __shared__ float dinv[256];
    __shared__ float sa[256];
    __shared__ float ss[256];
    __shared__ int   si_[256];
    __shared__ float scoreV[256];
    __shared__ int   kept[128];
    __shared__ int   rankOf[256];
    __shared__ float row[512];
    for (int e = t; e < EPG; e += 256) {
        size_t idx = (size_t)g * EPG + e;
        eb[e] = ((ei[idx] - g * 256) << 8) | (ei[E_TOT + idx] - g * 256);
    }
    curID[t] = t;
    float accMx = 0.f, accMn = 0.f;
    const float* GW[3] = {gw0, gw1, gw2};
    const float* GB[3] = {gb0, gb1, gb2};
    const float* PW[3] = {pw0, pw1, pw2};
    const int kk[3] = {128, 64, 32};
    int npg = 256;
    __syncthreads();
    for (int s = 0; s < 3; ++s) {
        const int knext = kk[s];
        {
            const float* Wp = GW[s];
            const int K = (s == 0) ? FIN : HF;
            for (int n = 0; n < npg; ++n) {
                if (s == 0) { if (t < FIN) sa[t] = x[(size_t)(g * 256 + n) * FIN + t]; }
                else sa[t] = P[(size_t)n * HF + t];
                __syncthreads();
                float a = 0.f;
                for (int k2 = 0; k2 < K; ++k2) a += sa[k2] * Wp[k2 * HF + t];
                Q[(size_t)n * HF + t] = a;
                __syncthreads();
            }
        }
        cntL[t] = 0;
        __syncthreads();
        for (int e = t; e < EPG; e += 256) {
            int p = eb[e];
            int cu = curID[p >> 8], cv = curID[p & 255];
            if (cu >= 0 && cv >= 0) atomicAdd(&cntL[cv], 1);
        }
        __syncthreads();
        if (t == 0) { int run = 0; for (int i = 0; i < npg; ++i) { startL[i] = run; run += cntL[i]; } }
        __syncthreads();
        if (t < npg) {
            float d = (float)cntL[t] + 1.0f;
            degF[t] = d;
            dinv[t] = 1.0f / sqrtf(d);
            int c = startL[t];
            for (int e = 0; e < EPG; ++e) {
                int p = eb[e];
                int cu = curID[p >> 8], cv = curID[p & 255];
                if (cu >= 0 && cv >= 0 && cv == t) slots[c++] = e;
            }
        }
        __syncthreads();
        {
            const float bb = GB[s][t];
            for (int n = 0; n < npg; ++n) {
                float acc = 0.f;
                const int s0 = startL[n], s1 = s0 + cntL[n];
                for (int j = s0; j < s1; ++j) {
                    int scur = curID[eb[slots[j]] >> 8];
                    acc += dinv[scur] * Q[(size_t)scur * HF + t];
                }
                float v = acc * dinv[n] + Q[(size_t)n * HF + t] / degF[n] + bb;
                P[(size_t)n * HF + t] = fmaxf(v, 0.f);
            }
        }
        __syncthreads();
        {
            const float* pwp = PW[s];
            const int lane = t & 63, wv = t >> 6;
            float s2p = 0.f;
            for (int j = 0; j < 4; ++j) { float w = pwp[lane + 64 * j]; s2p += w * w; }
            for (int off = 32; off; off >>= 1) s2p += __shfl_down(s2p, off, 64);
            s2p = __shfl(s2p, 0, 64);
            const float nw = sqrtf(s2p);
            for (int n = wv; n < npg; n += 4) {
                float pr = 0.f;
                for (int j = 0; j < 4; ++j) { int f = lane + 64 * j; pr += P[(size_t)n * HF + f] * pwp[f]; }
                for (int off = 32; off; off >>= 1) pr += __shfl_down(pr, off, 64);
                if (lane == 0) scoreV[n] = tanhf(pr / nw);
            }
        }
        __syncthreads();
        if (t < npg) { ss[t] = scoreV[t]; si_[t] = t; }
        else         { ss[t] = -INFINITY; si_[t] = 0x7FFFFFFF; }
        for (int size = 2; size <= 256; size <<= 1) {
            for (int stride = size >> 1; stride > 0; stride >>= 1) {
                __syncthreads();
                int i = t, j = t ^ stride;
                if (j > i) {
                    float a = ss[i], b = ss[j];
                    int ia = si_[i], ib = si_[j];
                    bool inOrder = (a > b) || (a == b && ia < ib);
                    bool desc = ((i & size) == 0);
                    if (desc ? !inOrder : inOrder) { ss[i] = b; ss[j] = a; si_[i] = ib; si_[j] = ia; }
                }
            }
        }
        __syncthreads();
        if (t < knext) kept[t] = si_[t];
        __syncthreads();
        {
            float mx = -INFINITY, sm = 0.f;
            for (int n = 0; n < knext; ++n) {
                int o = kept[n];
                float vv = P[(size_t)o * HF + t] * scoreV[o];
                Q[(size_t)n * HF + t] = vv;
                mx = fmaxf(mx, vv);
                sm += vv;
            }
            accMx += mx;
            accMn += sm / (float)knext;
        }
        rankOf[t] = -1;
        __syncthreads();
        if (t < knext) rankOf[kept[t]] = t;
        __syncthreads();
        { int c = curID[t]; curID[t] = (c >= 0) ? rankOf[c] : -1; }
        __syncthreads();
        { float* tmp = P; P = Q; Q = tmp; }
        npg = knext;
    }
    row[t] = accMx;
    row[256 + t] = accMn;
    __syncthreads();
    { float a = l1b[t]; for (int j = 0; j < 512; ++j) a += row[j] * l1w[j * 256 + t]; scoreV[t] = fmaxf(a, 0.f); }
    __syncthreads();
    if (t < 128) { float a2 = l2b[t]; for (int j = 0; j < 256; ++j) a2 += scoreV[j] * l2w[j * 128 + t]; sa[t] = fmaxf(a2, 0.f); }
    __syncthreads();
    if (t == 0) {
        float l0 = l3b[0], l1 = l3b[1];
        for (int j = 0; j < 128; ++j) { float h = sa[j]; l0 += h * l3w[j * 2 + 0]; l1 += h * l3w[j * 2 + 1]; }
        float m = fmaxf(l0, l1);
        float lse = m + logf(expf(l0 - m) + expf(l1 - m));
        out[g * 2 + 0] = l0 - lse;
        out[g * 2 + 1] = l1 - lse;
    }
}

// ============================================================================
extern "C" void kernel_launch(void* const* d_in, const int* in_sizes, int n_in,
                              void* d_out, int out_size, void* d_ws, size_t ws_size,
                              hipStream_t stream) {
    const float* x   = (const float*)d_in[0];
    const int*   ei  = (const int*)d_in[1];
    const float* gw0 = (const float*)d_in[3];
    const float* gb0 = (const float*)d_in[4];
    const float* gw1 = (const float*)d_in[5];
    const float* gb1 = (const float*)d_in[6];
    const float* gw2 = (const float*)d_in[7];
    const float* gb2 = (const float*)d_in[8];
    const float* pw0 = (const float*)d_in[9];
    const float* pw1 = (const float*)d_in[10];
    const float* pw2 = (const float*)d_in[11];
    const float* l1w = (const float*)d_in[12];
    const float* l1b = (const float*)d_in[13];
    const float* l2w = (const float*)d_in[14];
    const float* l2b = (const float*)d_in[15];
    const float* l3w = (const float*)d_in[16];
    const float* l3b = (const float*)d_in[17];
    float* out = (float*)d_out;

    const size_t SLAB = (size_t)65536 * 256;
    char* p = (char*)d_ws;
    float* P      = (float*)p; p += SLAB * 4;
    float* Q      = (float*)p; p += SLAB * 4;
    int*   cur    = (int*)p;   p += (size_t)65536 * 4;
    int*   degS   = (int*)p;   p += (size_t)65536 * 4;
    float* dinvS  = (float*)p; p += (size_t)65536 * 4;
    int*   starts = (int*)p;   p += (size_t)65536 * 4;
    int2*  slots2 = (int2*)p;  p += (size_t)E_TOT * 8;
    float* score  = (float*)p; p += (size_t)65536 * 4;
    int*   kept   = (int*)p;   p += (size_t)32768 * 4;
    float* outacc = (float*)p; p += (size_t)G_GRAPHS * 512 * 4;
    const size_t needed = (size_t)(p - (char*)d_ws);

    if (ws_size < needed) {
        gnn_mono<<<G_GRAPHS, 256, 0, stream>>>(
            x, ei, gw0, gb0, gw1, gb1, gw2, gb2, pw0, pw1, pw2,
            l1w, l1b, l2w, l2b, l3w, l3b, out, (float*)d_ws);
        return;
    }

    const int   npg[3] = {256, 128, 64};
    const int   kk[3]  = {128, 64, 32};
    const int   Ns[3]  = {65536, 32768, 16384};
    const float* GW[3] = {gw0, gw1, gw2};
    const float* GB[3] = {gb0, gb1, gb2};
    const float* PW[3] = {pw0, pw1, pw2};

    float* HLs[3]   = {P, Q, P};
    float* H2s[3]   = {Q, P, Q};
    float* POOLs[3] = {P, Q, P};

    // init cur + CSR(0), fused
    fused_init_csr<<<G_GRAPHS, 256, 0, stream>>>(ei, cur, degS, dinvS,
                                                 starts, slots2);

    for (int s = 0; s < 3; ++s) {
        const int n = Ns[s];
        const int k = kk[s];
        // 1) GEMM: v12 (8x8, LDS-ratio 1.5) for s0/s1; v8 for s2 (grid)
        if (s == 0) {
            gemm_v12<FIN><<<dim3(n / 128, 2), 256, 0, stream>>>(x, GW[s], HLs[s]);
        } else if (s == 1) {
            gemm_v12<HF><<<dim3(n / 128, 2), 256, 0, stream>>>(POOLs[s - 1], GW[s], HLs[s]);
        } else {
            gemm_v8<HF><<<dim3(n / 64, 2), 256, 0, stream>>>(POOLs[s - 1], GW[s], HLs[s]);
        }
        // 2) conv + score (wave-per-node, float4 gathers)
        agg_score2<<<n / 4, 256, 0, stream>>>(degS, dinvS, starts, slots2,
                                              HLs[s], H2s[s], GB[s], PW[s], score,
                                              n / 32);
        // 3) topk + pool + readout (+ CSR of next stage, or MLP at the end)
        if (s < 2) {
            fused_topk_csr<<<G_GRAPHS, 256, 0, stream>>>(
                score, npg[s], k, H2s[s], POOLs[s], outacc, cur, s == 0 ? 1 : 0,
                ei, degS, dinvS, starts, slots2);
        } else {
            fused_topk_mlp<<<G_GRAPHS, 256, 0, stream>>>(
                score, npg[s], k, H2s[s], outacc,
                l1w, l1b, l2w, l2b, l3w, l3b, out);
        }
    }
}